// Round 3
// baseline (27429.224 us; speedup 1.0000x reference)
//
#include <hip/hip_runtime.h>
#include <stdint.h>

// Problem constants
#define BB   64
#define TT   512
#define HT   256
#define OO   128
#define GATES 1024   // 4*H

// lstm weight-persistence split (units of "kq" = 4 consecutive k values;
// per kq per thread: 2 float4 = rows (2t,2t+1) x k[4u..4u+3])
#define UREG 18                    // kq held in VGPRs (36 f4 = 144 VGPR/lane)
#define ULDS 7                     // kq held in LDS   (7*2*512 f4 = 112 KB)
#define USTR (64 - UREG - ULDS)    // 39 kq streamed from L2 each step (624 KB)

__device__ __forceinline__ float sigmoidf_(float x) {
    return 1.0f / (1.0f + __expf(-x));
}

// ---------------------------------------------------------------------------
// Embedding gather + decoder_action output
__global__ __launch_bounds__(256) void embed_kernel(
    const int* __restrict__ actions, const float* __restrict__ emb_table,
    float* __restrict__ X, float* __restrict__ dact)
{
    int row = blockIdx.x;
    int t = row & (TT - 1);
    int id = (t == 0) ? 0 : actions[row - 1];
    X[(int64_t)row * HT + threadIdx.x] = emb_table[(int64_t)id * HT + threadIdx.x];
    if (threadIdx.x == 0) dact[row] = (float)actions[row];
}

// ---------------------------------------------------------------------------
// Repack Whh into the lstm load layout:
// Wpk4[l*65536 + (u*2+f)*512 + t] = float4 of Whh[l][2t+f][4u .. 4u+3]
// grid: 512 blocks x 256 threads (131072 float4s total)
__global__ __launch_bounds__(256) void repack_whh_kernel(
    const float* __restrict__ Whh, float4* __restrict__ Wpk4)
{
    int fl = blockIdx.x * 256 + threadIdx.x;   // 0..131071
    int l   = fl >> 16;
    int rem = fl & 65535;
    int uf  = rem >> 9;          // 0..127
    int t   = rem & 511;
    int u   = uf >> 1;
    int f   = uf & 1;
    Wpk4[fl] = *(const float4*)(Whh + (int64_t)l * (GATES * HT)
                                    + (int64_t)(2 * t + f) * HT + 4 * u);
}

// ---------------------------------------------------------------------------
// Generic fp32 tiled GEMM: C = act( A @ op(B) + bias1 + bias2 )
// BM=BN=128, BK=16, 256 threads, 8x8 per thread. Dims divisible.
template<bool TRANS_B, int ACT>
__global__ __launch_bounds__(256) void gemm128_kernel(
    const float* __restrict__ A, const float* __restrict__ Bm,
    float* __restrict__ C,
    int K, int lda, int ldb, int ldc,
    int64_t sA, int64_t sB, int64_t sC,
    const float* __restrict__ bias1, const float* __restrict__ bias2)
{
    constexpr int BM = 128, BN = 128, BK = 16;
    __shared__ __align__(16) float As[BK][BM + 4];
    __shared__ __align__(16) float Bs[BK][BN + 4];

    const int tid = threadIdx.x;
    const int m0 = blockIdx.y * BM;
    const int n0 = blockIdx.x * BN;
    A  += (int64_t)blockIdx.z * sA;
    Bm += (int64_t)blockIdx.z * sB;
    C  += (int64_t)blockIdx.z * sC;

    const int tm = tid & 15;
    const int tn = tid >> 4;

    float acc[8][8] = {};

    for (int k0 = 0; k0 < K; k0 += BK) {
        #pragma unroll
        for (int i = 0; i < 2; i++) {
            int idx = tid + i * 256;
            int ar = idx >> 2;
            int ak = (idx & 3) * 4;
            const float4 v = *(const float4*)(A + (int64_t)(m0 + ar) * lda + k0 + ak);
            As[ak + 0][ar] = v.x; As[ak + 1][ar] = v.y;
            As[ak + 2][ar] = v.z; As[ak + 3][ar] = v.w;
        }
        if (TRANS_B) {
            #pragma unroll
            for (int i = 0; i < 2; i++) {
                int idx = tid + i * 256;
                int br = idx >> 2;
                int bk = (idx & 3) * 4;
                const float4 v = *(const float4*)(Bm + (int64_t)(n0 + br) * ldb + k0 + bk);
                Bs[bk + 0][br] = v.x; Bs[bk + 1][br] = v.y;
                Bs[bk + 2][br] = v.z; Bs[bk + 3][br] = v.w;
            }
        } else {
            #pragma unroll
            for (int i = 0; i < 2; i++) {
                int idx = tid + i * 256;
                int bk = idx >> 5;
                int bn = (idx & 31) * 4;
                const float4 v = *(const float4*)(Bm + (int64_t)(k0 + bk) * ldb + n0 + bn);
                *(float4*)&Bs[bk][bn] = v;
            }
        }
        __syncthreads();

        #pragma unroll
        for (int k = 0; k < BK; k++) {
            float a[8], b[8];
            *(float4*)&a[0] = *(const float4*)&As[k][tm * 8];
            *(float4*)&a[4] = *(const float4*)&As[k][tm * 8 + 4];
            *(float4*)&b[0] = *(const float4*)&Bs[k][tn * 8];
            *(float4*)&b[4] = *(const float4*)&Bs[k][tn * 8 + 4];
            #pragma unroll
            for (int i = 0; i < 8; i++)
                #pragma unroll
                for (int j = 0; j < 8; j++)
                    acc[i][j] += a[i] * b[j];
        }
        __syncthreads();
    }

    float bv[8];
    #pragma unroll
    for (int j = 0; j < 8; j++) {
        int n = n0 + tn * 8 + j;
        float b = 0.0f;
        if (bias1) b += bias1[n];
        if (bias2) b += bias2[n];
        bv[j] = b;
    }
    #pragma unroll
    for (int i = 0; i < 8; i++) {
        int64_t m = m0 + tm * 8 + i;
        float o[8];
        #pragma unroll
        for (int j = 0; j < 8; j++) {
            float v = acc[i][j] + bv[j];
            if (ACT == 1) v = tanhf(v);
            o[j] = v;
        }
        *(float4*)(C + m * ldc + n0 + tn * 8)     = make_float4(o[0], o[1], o[2], o[3]);
        *(float4*)(C + m * ldc + n0 + tn * 8 + 4) = make_float4(o[4], o[5], o[6], o[7]);
    }
}

// ---------------------------------------------------------------------------
// LSTM recurrence, weight-persistent single-workgroup version.
// grid: 64 blocks (one per batch) x 512 threads.
// Thread t owns gate rows (2t, 2t+1). Weight source per kq u (k = 4u..4u+3):
//   u <  UREG          : VGPRs (loaded once)
//   u <  UREG+ULDS     : LDS   (staged once)
//   else               : streamed from L2 every step
// All cross-step state (h in LDS, c in regs) is workgroup-local; 2 barriers/step.
__global__ __launch_bounds__(512, 2) void lstm_rec_kernel(
    const float* __restrict__ Ag,      // [B*T][1024] = x@Wih^T + bih + bhh
    const float4* __restrict__ Wpk,    // this layer's packed weights
    const float* __restrict__ h0,      // [B][256] this layer
    const float* __restrict__ c0,
    float* __restrict__ X, int ldx)    // h output, row b*T+t
{
    const int b = blockIdx.x;
    const int t = threadIdx.x;         // 0..511

    __shared__ __align__(16) float  hsh[HT];
    __shared__ __align__(16) float  gsh[GATES];
    __shared__ __align__(16) float4 Wl[ULDS * 2 * 512];   // 112 KB

    // --- weights into registers (144 VGPRs)
    float4 wreg[2 * UREG];
    #pragma unroll
    for (int u = 0; u < UREG; u++) {
        wreg[2 * u]     = Wpk[(u * 2 + 0) * 512 + t];
        wreg[2 * u + 1] = Wpk[(u * 2 + 1) * 512 + t];
    }
    // --- weights into LDS (once)
    #pragma unroll
    for (int v = 0; v < ULDS; v++) {
        Wl[(v * 2 + 0) * 512 + t] = Wpk[((UREG + v) * 2 + 0) * 512 + t];
        Wl[(v * 2 + 1) * 512 + t] = Wpk[((UREG + v) * 2 + 1) * 512 + t];
    }
    const float4* __restrict__ Ws = Wpk + (UREG + ULDS) * 2 * 512;

    // --- state init
    if (t < HT) hsh[t] = h0[b * HT + t];
    float c = (t < HT) ? c0[b * HT + t] : 0.0f;
    __syncthreads();

    const float4* hsh4 = (const float4*)hsh;
    const float* AgB = Ag + (int64_t)b * TT * GATES;

    for (int st = 0; st < TT; st++) {
        float2 acc = *(const float2*)(AgB + (int64_t)st * GATES + 2 * t);

        #pragma unroll
        for (int u = 0; u < UREG; u++) {
            float4 h4 = hsh4[u];
            float4 wa = wreg[2 * u], wb = wreg[2 * u + 1];
            acc.x += wa.x * h4.x + wa.y * h4.y + wa.z * h4.z + wa.w * h4.w;
            acc.y += wb.x * h4.x + wb.y * h4.y + wb.z * h4.z + wb.w * h4.w;
        }
        #pragma unroll
        for (int v = 0; v < ULDS; v++) {
            float4 h4 = hsh4[UREG + v];
            float4 wa = Wl[(v * 2 + 0) * 512 + t];
            float4 wb = Wl[(v * 2 + 1) * 512 + t];
            acc.x += wa.x * h4.x + wa.y * h4.y + wa.z * h4.z + wa.w * h4.w;
            acc.y += wb.x * h4.x + wb.y * h4.y + wb.z * h4.z + wb.w * h4.w;
        }
        #pragma unroll
        for (int u = 0; u < USTR; u++) {
            float4 h4 = hsh4[UREG + ULDS + u];
            float4 wa = Ws[(u * 2 + 0) * 512 + t];
            float4 wb = Ws[(u * 2 + 1) * 512 + t];
            acc.x += wa.x * h4.x + wa.y * h4.y + wa.z * h4.z + wa.w * h4.w;
            acc.y += wb.x * h4.x + wb.y * h4.y + wb.z * h4.z + wb.w * h4.w;
        }
        *(float2*)&gsh[2 * t] = acc;
        __syncthreads();                       // gates complete

        if (t < HT) {
            float gi = gsh[t];
            float gf = gsh[HT + t];
            float gg = gsh[2 * HT + t];
            float go = gsh[3 * HT + t];
            c = sigmoidf_(gf) * c + sigmoidf_(gi) * tanhf(gg);
            float h = sigmoidf_(go) * tanhf(c);
            X[((int64_t)b * TT + st) * ldx + t] = h;
            hsh[t] = h;                        // safe: dots done at barrier above
        }
        __syncthreads();                       // h visible for next step
    }
}

// ---------------------------------------------------------------------------
__global__ __launch_bounds__(256) void softmax512_kernel(float* __restrict__ S)
{
    int row = blockIdx.x * 4 + (threadIdx.x >> 6);
    int lane = threadIdx.x & 63;
    float* p = S + (int64_t)row * 512 + lane * 8;
    float4 v0 = *(float4*)p;
    float4 v1 = *(float4*)(p + 4);
    float m = fmaxf(fmaxf(fmaxf(v0.x, v0.y), fmaxf(v0.z, v0.w)),
                    fmaxf(fmaxf(v1.x, v1.y), fmaxf(v1.z, v1.w)));
    #pragma unroll
    for (int off = 32; off; off >>= 1) m = fmaxf(m, __shfl_xor(m, off));
    v0.x = __expf(v0.x - m); v0.y = __expf(v0.y - m);
    v0.z = __expf(v0.z - m); v0.w = __expf(v0.w - m);
    v1.x = __expf(v1.x - m); v1.y = __expf(v1.y - m);
    v1.z = __expf(v1.z - m); v1.w = __expf(v1.w - m);
    float s = v0.x + v0.y + v0.z + v0.w + v1.x + v1.y + v1.z + v1.w;
    #pragma unroll
    for (int off = 32; off; off >>= 1) s += __shfl_xor(s, off);
    float inv = 1.0f / s;
    v0.x *= inv; v0.y *= inv; v0.z *= inv; v0.w *= inv;
    v1.x *= inv; v1.y *= inv; v1.z *= inv; v1.w *= inv;
    *(float4*)p = v0;
    *(float4*)(p + 4) = v1;
}

__global__ __launch_bounds__(256) void values_kernel(
    const float* __restrict__ Q, const float* __restrict__ L, float* __restrict__ V)
{
    int row = blockIdx.x * 4 + (threadIdx.x >> 6);
    int lane = threadIdx.x & 63;
    float2 q = *(const float2*)(Q + (int64_t)row * OO + lane * 2);
    float2 l = *(const float2*)(L + (int64_t)row * OO + lane * 2);
    float s = q.x * l.x + q.y * l.y;
    #pragma unroll
    for (int off = 32; off; off >>= 1) s += __shfl_xor(s, off);
    if (lane == 0) V[row] = s;
}

// ---------------------------------------------------------------------------
extern "C" void kernel_launch(void* const* d_in, const int* in_sizes, int n_in,
                              void* d_out, int out_size, void* d_ws, size_t ws_size,
                              hipStream_t stream)
{
    const float* enc      = (const float*)d_in[0];
    const float* h0       = (const float*)d_in[1];
    const float* c0       = (const float*)d_in[2];
    const int*   actions  = (const int*)  d_in[3];
    const float* emb_t    = (const float*)d_in[4];
    const float* Wih      = (const float*)d_in[5];
    const float* Whh      = (const float*)d_in[6];
    const float* bih      = (const float*)d_in[7];
    const float* bhh      = (const float*)d_in[8];
    const float* W_attn   = (const float*)d_in[9];
    const float* b_attn   = (const float*)d_in[10];
    const float* W_concat = (const float*)d_in[11];
    const float* b_concat = (const float*)d_in[12];
    const float* W_out    = (const float*)d_in[13];
    const float* W_critic = (const float*)d_in[14];
    const float* b_critic = (const float*)d_in[15];
    (void)in_sizes; (void)n_in; (void)out_size; (void)ws_size;

    const int M = BB * TT;                 // 32768

    float* out    = (float*)d_out;
    float* dact   = out;
    float* logits = out + M;
    float* values = out + M + (int64_t)M * OO;

    // Workspace arena (floats), 256 MiB total:
    //   gates : 33,554,432   (A; later scores then qv)
    //   xbuf  :  8,388,608   (emb -> X1 -> dec)
    //   cat   : 16,777,216   ([out | ctx] row stride 512)
    //   keysR :  8,388,608   (Wpk during LSTM; keys after)
    float* ws    = (float*)d_ws;
    float* gates = ws;
    float* xbuf  = ws + 33554432;
    float* cat   = ws + 41943040;
    float* keysR = ws + 58720256;
    float* keys  = keysR;
    float4* Wpk4 = (float4*)keysR;         // 131072 float4 = 2 MB; dead before keys
    float* scores = gates;
    float* qv     = gates;
    float* dec    = xbuf;

    const int64_t LWP = 65536;             // float4s per layer in Wpk

    // 1) embedding + decoder_action
    hipLaunchKernelGGL(embed_kernel, dim3(M), dim3(256), 0, stream,
                       actions, emb_t, xbuf, dact);
    // 2) repack Whh into register/LDS/stream layout
    hipLaunchKernelGGL(repack_whh_kernel, dim3(512), dim3(256), 0, stream,
                       Whh, Wpk4);
    // 3) layer-0 input GEMM: gates = emb @ Wih0^T + bih0 + bhh0
    hipLaunchKernelGGL((gemm128_kernel<true, 0>), dim3(8, 256, 1), dim3(256), 0, stream,
                       xbuf, Wih, gates, HT, HT, HT, GATES,
                       (int64_t)0, (int64_t)0, (int64_t)0, bih, bhh);
    // 4) layer-0 recurrence -> X1 (xbuf, ldx=256)
    hipLaunchKernelGGL(lstm_rec_kernel, dim3(BB), dim3(512), 0, stream,
                       gates, Wpk4, h0, c0, xbuf, HT);
    // 5) layer-1 input GEMM
    hipLaunchKernelGGL((gemm128_kernel<true, 0>), dim3(8, 256, 1), dim3(256), 0, stream,
                       xbuf, Wih + (int64_t)GATES * HT, gates, HT, HT, HT, GATES,
                       (int64_t)0, (int64_t)0, (int64_t)0, bih + GATES, bhh + GATES);
    // 6) layer-1 recurrence -> cat[:, 0:256] (ldx=512)
    hipLaunchKernelGGL(lstm_rec_kernel, dim3(BB), dim3(512), 0, stream,
                       gates, Wpk4 + LWP, h0 + BB * HT, c0 + BB * HT, cat, 2 * HT);
    // 7) keys = enc @ W_attn^T + b_attn   (overwrites Wpk region)
    hipLaunchKernelGGL((gemm128_kernel<true, 0>), dim3(2, 256, 1), dim3(256), 0, stream,
                       enc, W_attn, keys, HT, HT, HT, HT,
                       (int64_t)0, (int64_t)0, (int64_t)0, b_attn, (const float*)nullptr);
    // 8) scores[b] = out[b] @ keys[b]^T
    hipLaunchKernelGGL((gemm128_kernel<true, 0>), dim3(4, 4, BB), dim3(256), 0, stream,
                       cat, keys, scores, HT, 2 * HT, HT, TT,
                       (int64_t)TT * 2 * HT, (int64_t)TT * HT, (int64_t)TT * TT,
                       (const float*)nullptr, (const float*)nullptr);
    // 9) softmax
    hipLaunchKernelGGL(softmax512_kernel, dim3(M / 4), dim3(256), 0, stream, scores);
    // 10) ctx[b] = P[b] @ enc[b] -> cat[:,256:]
    hipLaunchKernelGGL((gemm128_kernel<false, 0>), dim3(2, 4, BB), dim3(256), 0, stream,
                       scores, enc, cat + HT, TT, TT, HT, 2 * HT,
                       (int64_t)TT * TT, (int64_t)TT * HT, (int64_t)TT * 2 * HT,
                       (const float*)nullptr, (const float*)nullptr);
    // 11) dec = tanh(cat @ W_concat^T + b_concat)
    hipLaunchKernelGGL((gemm128_kernel<true, 1>), dim3(2, 256, 1), dim3(256), 0, stream,
                       cat, W_concat, dec, 2 * HT, 2 * HT, 2 * HT, HT,
                       (int64_t)0, (int64_t)0, (int64_t)0, b_concat, (const float*)nullptr);
    // 12) logits = dec @ W_out^T
    hipLaunchKernelGGL((gemm128_kernel<true, 0>), dim3(1, 256, 1), dim3(256), 0, stream,
                       dec, W_out, logits, HT, HT, HT, OO,
                       (int64_t)0, (int64_t)0, (int64_t)0,
                       (const float*)nullptr, (const float*)nullptr);
    // 13) qv = logits @ W_critic^T + b_critic
    hipLaunchKernelGGL((gemm128_kernel<true, 0>), dim3(1, 256, 1), dim3(256), 0, stream,
                       logits, W_critic, qv, OO, OO, OO, OO,
                       (int64_t)0, (int64_t)0, (int64_t)0, b_critic, (const float*)nullptr);
    // 14) values
    hipLaunchKernelGGL(values_kernel, dim3(M / 4), dim3(256), 0, stream,
                       qv, logits, values);
}

// Round 4
// 26945.114 us; speedup vs baseline: 1.0180x; 1.0180x over previous
//
#include <hip/hip_runtime.h>
#include <stdint.h>

// Problem constants
#define BB   64
#define TT   512
#define HT   256
#define OO   128
#define GATES 1024   // 4*H

// lstm weight-persistence split (units of "kq" = 4 consecutive k values;
// per kq per thread: 2 float4 = rows (2t,2t+1) x k[4u..4u+3]; 16 KB/unit)
#define UREG 22                    // kq in VGPRs: 44 f4 = 176 VGPR/lane (352 KB/CU)
#define ULDS 9                     // kq in LDS: 9*2*512 f4 = 144 KB
#define USTR (64 - UREG - ULDS)    // 33 kq streamed from L2 each step (528 KB)

__device__ __forceinline__ float sigmoidf_(float x) {
    return 1.0f / (1.0f + __expf(-x));
}

// ---------------------------------------------------------------------------
// Embedding gather + decoder_action output
__global__ __launch_bounds__(256) void embed_kernel(
    const int* __restrict__ actions, const float* __restrict__ emb_table,
    float* __restrict__ X, float* __restrict__ dact)
{
    int row = blockIdx.x;
    int t = row & (TT - 1);
    int id = (t == 0) ? 0 : actions[row - 1];
    X[(int64_t)row * HT + threadIdx.x] = emb_table[(int64_t)id * HT + threadIdx.x];
    if (threadIdx.x == 0) dact[row] = (float)actions[row];
}

// ---------------------------------------------------------------------------
// Repack Whh into the lstm load layout:
// Wpk4[l*65536 + (u*2+f)*512 + t] = float4 of Whh[l][2t+f][4u .. 4u+3]
__global__ __launch_bounds__(256) void repack_whh_kernel(
    const float* __restrict__ Whh, float4* __restrict__ Wpk4)
{
    int fl = blockIdx.x * 256 + threadIdx.x;   // 0..131071
    int l   = fl >> 16;
    int rem = fl & 65535;
    int uf  = rem >> 9;          // 0..127
    int t   = rem & 511;
    int u   = uf >> 1;
    int f   = uf & 1;
    Wpk4[fl] = *(const float4*)(Whh + (int64_t)l * (GATES * HT)
                                    + (int64_t)(2 * t + f) * HT + 4 * u);
}

// ---------------------------------------------------------------------------
// Generic fp32 tiled GEMM: C = act( A @ op(B) + bias1 + bias2 )
// BM=BN=128, BK=16, 256 threads, 8x8 per thread. Dims divisible.
template<bool TRANS_B, int ACT>
__global__ __launch_bounds__(256) void gemm128_kernel(
    const float* __restrict__ A, const float* __restrict__ Bm,
    float* __restrict__ C,
    int K, int lda, int ldb, int ldc,
    int64_t sA, int64_t sB, int64_t sC,
    const float* __restrict__ bias1, const float* __restrict__ bias2)
{
    constexpr int BM = 128, BN = 128, BK = 16;
    __shared__ __align__(16) float As[BK][BM + 4];
    __shared__ __align__(16) float Bs[BK][BN + 4];

    const int tid = threadIdx.x;
    const int m0 = blockIdx.y * BM;
    const int n0 = blockIdx.x * BN;
    A  += (int64_t)blockIdx.z * sA;
    Bm += (int64_t)blockIdx.z * sB;
    C  += (int64_t)blockIdx.z * sC;

    const int tm = tid & 15;
    const int tn = tid >> 4;

    float acc[8][8] = {};

    for (int k0 = 0; k0 < K; k0 += BK) {
        #pragma unroll
        for (int i = 0; i < 2; i++) {
            int idx = tid + i * 256;
            int ar = idx >> 2;
            int ak = (idx & 3) * 4;
            const float4 v = *(const float4*)(A + (int64_t)(m0 + ar) * lda + k0 + ak);
            As[ak + 0][ar] = v.x; As[ak + 1][ar] = v.y;
            As[ak + 2][ar] = v.z; As[ak + 3][ar] = v.w;
        }
        if (TRANS_B) {
            #pragma unroll
            for (int i = 0; i < 2; i++) {
                int idx = tid + i * 256;
                int br = idx >> 2;
                int bk = (idx & 3) * 4;
                const float4 v = *(const float4*)(Bm + (int64_t)(n0 + br) * ldb + k0 + bk);
                Bs[bk + 0][br] = v.x; Bs[bk + 1][br] = v.y;
                Bs[bk + 2][br] = v.z; Bs[bk + 3][br] = v.w;
            }
        } else {
            #pragma unroll
            for (int i = 0; i < 2; i++) {
                int idx = tid + i * 256;
                int bk = idx >> 5;
                int bn = (idx & 31) * 4;
                const float4 v = *(const float4*)(Bm + (int64_t)(k0 + bk) * ldb + n0 + bn);
                *(float4*)&Bs[bk][bn] = v;
            }
        }
        __syncthreads();

        #pragma unroll
        for (int k = 0; k < BK; k++) {
            float a[8], b[8];
            *(float4*)&a[0] = *(const float4*)&As[k][tm * 8];
            *(float4*)&a[4] = *(const float4*)&As[k][tm * 8 + 4];
            *(float4*)&b[0] = *(const float4*)&Bs[k][tn * 8];
            *(float4*)&b[4] = *(const float4*)&Bs[k][tn * 8 + 4];
            #pragma unroll
            for (int i = 0; i < 8; i++)
                #pragma unroll
                for (int j = 0; j < 8; j++)
                    acc[i][j] += a[i] * b[j];
        }
        __syncthreads();
    }

    float bv[8];
    #pragma unroll
    for (int j = 0; j < 8; j++) {
        int n = n0 + tn * 8 + j;
        float b = 0.0f;
        if (bias1) b += bias1[n];
        if (bias2) b += bias2[n];
        bv[j] = b;
    }
    #pragma unroll
    for (int i = 0; i < 8; i++) {
        int64_t m = m0 + tm * 8 + i;
        float o[8];
        #pragma unroll
        for (int j = 0; j < 8; j++) {
            float v = acc[i][j] + bv[j];
            if (ACT == 1) v = tanhf(v);
            o[j] = v;
        }
        *(float4*)(C + m * ldc + n0 + tn * 8)     = make_float4(o[0], o[1], o[2], o[3]);
        *(float4*)(C + m * ldc + n0 + tn * 8 + 4) = make_float4(o[4], o[5], o[6], o[7]);
    }
}

// ---------------------------------------------------------------------------
// LSTM recurrence, weight-persistent single-workgroup version.
// grid: 64 blocks (one per batch) x 512 threads = 8 waves = 2 waves/EU.
// amdgpu_waves_per_eu(2,2) PINS the allocator to the 256-VGPR budget so the
// 176 weight VGPRs are NOT spilled (R3: launch_bounds min-waves alone let the
// backend pick 4 waves/EU -> 128 VGPRs -> 10 GB of scratch thrash).
// Thread t owns gate rows (2t, 2t+1). Weight source per kq u (k = 4u..4u+3):
//   u < UREG        : VGPRs (loaded once)
//   u < UREG+ULDS   : LDS   (staged once)
//   else            : streamed from L2 every step
__global__ __attribute__((amdgpu_waves_per_eu(2, 2)))
__launch_bounds__(512) void lstm_rec_kernel(
    const float* __restrict__ Ag,      // [B*T][1024] = x@Wih^T + bih + bhh
    const float4* __restrict__ Wpk,    // this layer's packed weights
    const float* __restrict__ h0,      // [B][256] this layer
    const float* __restrict__ c0,
    float* __restrict__ X, int ldx)    // h output, row b*T+t
{
    const int b = blockIdx.x;
    const int t = threadIdx.x;         // 0..511

    __shared__ __align__(16) float  hsh[HT];
    __shared__ __align__(16) float  gsh[GATES];
    __shared__ __align__(16) float4 Wl[ULDS * 2 * 512];   // 144 KB

    // --- weights into registers (176 VGPRs)
    float4 wreg[2 * UREG];
    #pragma unroll
    for (int u = 0; u < UREG; u++) {
        wreg[2 * u]     = Wpk[(u * 2 + 0) * 512 + t];
        wreg[2 * u + 1] = Wpk[(u * 2 + 1) * 512 + t];
    }
    // --- weights into LDS (once)
    #pragma unroll
    for (int v = 0; v < ULDS; v++) {
        Wl[(v * 2 + 0) * 512 + t] = Wpk[((UREG + v) * 2 + 0) * 512 + t];
        Wl[(v * 2 + 1) * 512 + t] = Wpk[((UREG + v) * 2 + 1) * 512 + t];
    }
    const float4* __restrict__ Ws = Wpk + (UREG + ULDS) * 2 * 512;

    // --- state init
    if (t < HT) hsh[t] = h0[b * HT + t];
    float c = (t < HT) ? c0[b * HT + t] : 0.0f;
    __syncthreads();

    const float4* hsh4 = (const float4*)hsh;
    const float* AgB = Ag + (int64_t)b * TT * GATES;

    for (int st = 0; st < TT; st++) {
        float2 acc = *(const float2*)(AgB + (int64_t)st * GATES + 2 * t);

        #pragma unroll
        for (int u = 0; u < UREG; u++) {
            float4 h4 = hsh4[u];
            float4 wa = wreg[2 * u], wb = wreg[2 * u + 1];
            acc.x += wa.x * h4.x + wa.y * h4.y + wa.z * h4.z + wa.w * h4.w;
            acc.y += wb.x * h4.x + wb.y * h4.y + wb.z * h4.z + wb.w * h4.w;
        }
        #pragma unroll
        for (int v = 0; v < ULDS; v++) {
            float4 h4 = hsh4[UREG + v];
            float4 wa = Wl[(v * 2 + 0) * 512 + t];
            float4 wb = Wl[(v * 2 + 1) * 512 + t];
            acc.x += wa.x * h4.x + wa.y * h4.y + wa.z * h4.z + wa.w * h4.w;
            acc.y += wb.x * h4.x + wb.y * h4.y + wb.z * h4.z + wb.w * h4.w;
        }
        #pragma unroll
        for (int u = 0; u < USTR; u++) {
            float4 h4 = hsh4[UREG + ULDS + u];
            float4 wa = Ws[(u * 2 + 0) * 512 + t];
            float4 wb = Ws[(u * 2 + 1) * 512 + t];
            acc.x += wa.x * h4.x + wa.y * h4.y + wa.z * h4.z + wa.w * h4.w;
            acc.y += wb.x * h4.x + wb.y * h4.y + wb.z * h4.z + wb.w * h4.w;
        }
        *(float2*)&gsh[2 * t] = acc;
        __syncthreads();                       // gates complete

        if (t < HT) {
            float gi = gsh[t];
            float gf = gsh[HT + t];
            float gg = gsh[2 * HT + t];
            float go = gsh[3 * HT + t];
            c = sigmoidf_(gf) * c + sigmoidf_(gi) * tanhf(gg);
            float h = sigmoidf_(go) * tanhf(c);
            X[((int64_t)b * TT + st) * ldx + t] = h;
            hsh[t] = h;                        // safe: dots done at barrier above
        }
        __syncthreads();                       // h visible for next step
    }
}

// ---------------------------------------------------------------------------
__global__ __launch_bounds__(256) void softmax512_kernel(float* __restrict__ S)
{
    int row = blockIdx.x * 4 + (threadIdx.x >> 6);
    int lane = threadIdx.x & 63;
    float* p = S + (int64_t)row * 512 + lane * 8;
    float4 v0 = *(float4*)p;
    float4 v1 = *(float4*)(p + 4);
    float m = fmaxf(fmaxf(fmaxf(v0.x, v0.y), fmaxf(v0.z, v0.w)),
                    fmaxf(fmaxf(v1.x, v1.y), fmaxf(v1.z, v1.w)));
    #pragma unroll
    for (int off = 32; off; off >>= 1) m = fmaxf(m, __shfl_xor(m, off));
    v0.x = __expf(v0.x - m); v0.y = __expf(v0.y - m);
    v0.z = __expf(v0.z - m); v0.w = __expf(v0.w - m);
    v1.x = __expf(v1.x - m); v1.y = __expf(v1.y - m);
    v1.z = __expf(v1.z - m); v1.w = __expf(v1.w - m);
    float s = v0.x + v0.y + v0.z + v0.w + v1.x + v1.y + v1.z + v1.w;
    #pragma unroll
    for (int off = 32; off; off >>= 1) s += __shfl_xor(s, off);
    float inv = 1.0f / s;
    v0.x *= inv; v0.y *= inv; v0.z *= inv; v0.w *= inv;
    v1.x *= inv; v1.y *= inv; v1.z *= inv; v1.w *= inv;
    *(float4*)p = v0;
    *(float4*)(p + 4) = v1;
}

__global__ __launch_bounds__(256) void values_kernel(
    const float* __restrict__ Q, const float* __restrict__ L, float* __restrict__ V)
{
    int row = blockIdx.x * 4 + (threadIdx.x >> 6);
    int lane = threadIdx.x & 63;
    float2 q = *(const float2*)(Q + (int64_t)row * OO + lane * 2);
    float2 l = *(const float2*)(L + (int64_t)row * OO + lane * 2);
    float s = q.x * l.x + q.y * l.y;
    #pragma unroll
    for (int off = 32; off; off >>= 1) s += __shfl_xor(s, off);
    if (lane == 0) V[row] = s;
}

// ---------------------------------------------------------------------------
extern "C" void kernel_launch(void* const* d_in, const int* in_sizes, int n_in,
                              void* d_out, int out_size, void* d_ws, size_t ws_size,
                              hipStream_t stream)
{
    const float* enc      = (const float*)d_in[0];
    const float* h0       = (const float*)d_in[1];
    const float* c0       = (const float*)d_in[2];
    const int*   actions  = (const int*)  d_in[3];
    const float* emb_t    = (const float*)d_in[4];
    const float* Wih      = (const float*)d_in[5];
    const float* Whh      = (const float*)d_in[6];
    const float* bih      = (const float*)d_in[7];
    const float* bhh      = (const float*)d_in[8];
    const float* W_attn   = (const float*)d_in[9];
    const float* b_attn   = (const float*)d_in[10];
    const float* W_concat = (const float*)d_in[11];
    const float* b_concat = (const float*)d_in[12];
    const float* W_out    = (const float*)d_in[13];
    const float* W_critic = (const float*)d_in[14];
    const float* b_critic = (const float*)d_in[15];
    (void)in_sizes; (void)n_in; (void)out_size; (void)ws_size;

    const int M = BB * TT;                 // 32768

    float* out    = (float*)d_out;
    float* dact   = out;
    float* logits = out + M;
    float* values = out + M + (int64_t)M * OO;

    // Workspace arena (floats), 256 MiB total:
    //   gates : 33,554,432   (A; later scores then qv)
    //   xbuf  :  8,388,608   (emb -> X1 -> dec)
    //   cat   : 16,777,216   ([out | ctx] row stride 512)
    //   keysR :  8,388,608   (Wpk during LSTM; keys after)
    float* ws    = (float*)d_ws;
    float* gates = ws;
    float* xbuf  = ws + 33554432;
    float* cat   = ws + 41943040;
    float* keysR = ws + 58720256;
    float* keys  = keysR;
    float4* Wpk4 = (float4*)keysR;         // 131072 float4 = 2 MB; dead before keys
    float* scores = gates;
    float* qv     = gates;
    float* dec    = xbuf;

    const int64_t LWP = 65536;             // float4s per layer in Wpk

    // 1) embedding + decoder_action
    hipLaunchKernelGGL(embed_kernel, dim3(M), dim3(256), 0, stream,
                       actions, emb_t, xbuf, dact);
    // 2) repack Whh into register/LDS/stream layout
    hipLaunchKernelGGL(repack_whh_kernel, dim3(512), dim3(256), 0, stream,
                       Whh, Wpk4);
    // 3) layer-0 input GEMM: gates = emb @ Wih0^T + bih0 + bhh0
    hipLaunchKernelGGL((gemm128_kernel<true, 0>), dim3(8, 256, 1), dim3(256), 0, stream,
                       xbuf, Wih, gates, HT, HT, HT, GATES,
                       (int64_t)0, (int64_t)0, (int64_t)0, bih, bhh);
    // 4) layer-0 recurrence -> X1 (xbuf, ldx=256)
    hipLaunchKernelGGL(lstm_rec_kernel, dim3(BB), dim3(512), 0, stream,
                       gates, Wpk4, h0, c0, xbuf, HT);
    // 5) layer-1 input GEMM
    hipLaunchKernelGGL((gemm128_kernel<true, 0>), dim3(8, 256, 1), dim3(256), 0, stream,
                       xbuf, Wih + (int64_t)GATES * HT, gates, HT, HT, HT, GATES,
                       (int64_t)0, (int64_t)0, (int64_t)0, bih + GATES, bhh + GATES);
    // 6) layer-1 recurrence -> cat[:, 0:256] (ldx=512)
    hipLaunchKernelGGL(lstm_rec_kernel, dim3(BB), dim3(512), 0, stream,
                       gates, Wpk4 + LWP, h0 + BB * HT, c0 + BB * HT, cat, 2 * HT);
    // 7) keys = enc @ W_attn^T + b_attn   (overwrites Wpk region)
    hipLaunchKernelGGL((gemm128_kernel<true, 0>), dim3(2, 256, 1), dim3(256), 0, stream,
                       enc, W_attn, keys, HT, HT, HT, HT,
                       (int64_t)0, (int64_t)0, (int64_t)0, b_attn, (const float*)nullptr);
    // 8) scores[b] = out[b] @ keys[b]^T
    hipLaunchKernelGGL((gemm128_kernel<true, 0>), dim3(4, 4, BB), dim3(256), 0, stream,
                       cat, keys, scores, HT, 2 * HT, HT, TT,
                       (int64_t)TT * 2 * HT, (int64_t)TT * HT, (int64_t)TT * TT,
                       (const float*)nullptr, (const float*)nullptr);
    // 9) softmax
    hipLaunchKernelGGL(softmax512_kernel, dim3(M / 4), dim3(256), 0, stream, scores);
    // 10) ctx[b] = P[b] @ enc[b] -> cat[:,256:]
    hipLaunchKernelGGL((gemm128_kernel<false, 0>), dim3(2, 4, BB), dim3(256), 0, stream,
                       scores, enc, cat + HT, TT, TT, HT, 2 * HT,
                       (int64_t)TT * TT, (int64_t)TT * HT, (int64_t)TT * 2 * HT,
                       (const float*)nullptr, (const float*)nullptr);
    // 11) dec = tanh(cat @ W_concat^T + b_concat)
    hipLaunchKernelGGL((gemm128_kernel<true, 1>), dim3(2, 256, 1), dim3(256), 0, stream,
                       cat, W_concat, dec, 2 * HT, 2 * HT, 2 * HT, HT,
                       (int64_t)0, (int64_t)0, (int64_t)0, b_concat, (const float*)nullptr);
    // 12) logits = dec @ W_out^T
    hipLaunchKernelGGL((gemm128_kernel<true, 0>), dim3(1, 256, 1), dim3(256), 0, stream,
                       dec, W_out, logits, HT, HT, HT, OO,
                       (int64_t)0, (int64_t)0, (int64_t)0,
                       (const float*)nullptr, (const float*)nullptr);
    // 13) qv = logits @ W_critic^T + b_critic
    hipLaunchKernelGGL((gemm128_kernel<true, 0>), dim3(1, 256, 1), dim3(256), 0, stream,
                       logits, W_critic, qv, OO, OO, OO, OO,
                       (int64_t)0, (int64_t)0, (int64_t)0, b_critic, (const float*)nullptr);
    // 14) values
    hipLaunchKernelGGL(values_kernel, dim3(M / 4), dim3(256), 0, stream,
                       qv, logits, values);
}

// Round 5
// 7481.771 us; speedup vs baseline: 3.6661x; 3.6014x over previous
//
#include <hip/hip_runtime.h>
#include <stdint.h>

// Problem constants
#define BB   64
#define TT   512
#define HT   256
#define OO   128
#define GATES 1024   // 4*H

// lstm weight-persistence split (units of "kq" = 4 consecutive k values;
// per kq per thread: 2 float4 = rows (2t,2t+1) x k[4u..4u+3]; 16 KB/unit)
// SIZED FOR THE 128-VGPR BUDGET: R3/R4 proved the allocator pins 512-thread
// blocks to 128 VGPRs regardless of launch_bounds/waves_per_eu, spilling
// anything bigger (9.7 GB/dispatch scratch thrash). 40 weight VGPRs + ~70
// working set fits under 128 with zero spill.
#define UREG 10                    // kq in VGPRs: 20 f4 = 80 B/lane (160 KB/CU)
#define ULDS 9                     // kq in LDS: 9*2*512 f4 = 144 KB
#define USTR (64 - UREG - ULDS)    // 45 kq streamed from L2 each step (720 KB)

__device__ __forceinline__ float sigmoidf_(float x) {
    return 1.0f / (1.0f + __expf(-x));
}

// ---------------------------------------------------------------------------
// Embedding gather + decoder_action output
__global__ __launch_bounds__(256) void embed_kernel(
    const int* __restrict__ actions, const float* __restrict__ emb_table,
    float* __restrict__ X, float* __restrict__ dact)
{
    int row = blockIdx.x;
    int t = row & (TT - 1);
    int id = (t == 0) ? 0 : actions[row - 1];
    X[(int64_t)row * HT + threadIdx.x] = emb_table[(int64_t)id * HT + threadIdx.x];
    if (threadIdx.x == 0) dact[row] = (float)actions[row];
}

// ---------------------------------------------------------------------------
// Repack Whh into the lstm load layout:
// Wpk4[l*65536 + (u*2+f)*512 + t] = float4 of Whh[l][2t+f][4u .. 4u+3]
__global__ __launch_bounds__(256) void repack_whh_kernel(
    const float* __restrict__ Whh, float4* __restrict__ Wpk4)
{
    int fl = blockIdx.x * 256 + threadIdx.x;   // 0..131071
    int l   = fl >> 16;
    int rem = fl & 65535;
    int uf  = rem >> 9;          // 0..127
    int t   = rem & 511;
    int u   = uf >> 1;
    int f   = uf & 1;
    Wpk4[fl] = *(const float4*)(Whh + (int64_t)l * (GATES * HT)
                                    + (int64_t)(2 * t + f) * HT + 4 * u);
}

// ---------------------------------------------------------------------------
// Generic fp32 tiled GEMM: C = act( A @ op(B) + bias1 + bias2 )
// BM=BN=128, BK=16, 256 threads, 8x8 per thread. Dims divisible.
template<bool TRANS_B, int ACT>
__global__ __launch_bounds__(256) void gemm128_kernel(
    const float* __restrict__ A, const float* __restrict__ Bm,
    float* __restrict__ C,
    int K, int lda, int ldb, int ldc,
    int64_t sA, int64_t sB, int64_t sC,
    const float* __restrict__ bias1, const float* __restrict__ bias2)
{
    constexpr int BM = 128, BN = 128, BK = 16;
    __shared__ __align__(16) float As[BK][BM + 4];
    __shared__ __align__(16) float Bs[BK][BN + 4];

    const int tid = threadIdx.x;
    const int m0 = blockIdx.y * BM;
    const int n0 = blockIdx.x * BN;
    A  += (int64_t)blockIdx.z * sA;
    Bm += (int64_t)blockIdx.z * sB;
    C  += (int64_t)blockIdx.z * sC;

    const int tm = tid & 15;
    const int tn = tid >> 4;

    float acc[8][8] = {};

    for (int k0 = 0; k0 < K; k0 += BK) {
        #pragma unroll
        for (int i = 0; i < 2; i++) {
            int idx = tid + i * 256;
            int ar = idx >> 2;
            int ak = (idx & 3) * 4;
            const float4 v = *(const float4*)(A + (int64_t)(m0 + ar) * lda + k0 + ak);
            As[ak + 0][ar] = v.x; As[ak + 1][ar] = v.y;
            As[ak + 2][ar] = v.z; As[ak + 3][ar] = v.w;
        }
        if (TRANS_B) {
            #pragma unroll
            for (int i = 0; i < 2; i++) {
                int idx = tid + i * 256;
                int br = idx >> 2;
                int bk = (idx & 3) * 4;
                const float4 v = *(const float4*)(Bm + (int64_t)(n0 + br) * ldb + k0 + bk);
                Bs[bk + 0][br] = v.x; Bs[bk + 1][br] = v.y;
                Bs[bk + 2][br] = v.z; Bs[bk + 3][br] = v.w;
            }
        } else {
            #pragma unroll
            for (int i = 0; i < 2; i++) {
                int idx = tid + i * 256;
                int bk = idx >> 5;
                int bn = (idx & 31) * 4;
                const float4 v = *(const float4*)(Bm + (int64_t)(k0 + bk) * ldb + n0 + bn);
                *(float4*)&Bs[bk][bn] = v;
            }
        }
        __syncthreads();

        #pragma unroll
        for (int k = 0; k < BK; k++) {
            float a[8], b[8];
            *(float4*)&a[0] = *(const float4*)&As[k][tm * 8];
            *(float4*)&a[4] = *(const float4*)&As[k][tm * 8 + 4];
            *(float4*)&b[0] = *(const float4*)&Bs[k][tn * 8];
            *(float4*)&b[4] = *(const float4*)&Bs[k][tn * 8 + 4];
            #pragma unroll
            for (int i = 0; i < 8; i++)
                #pragma unroll
                for (int j = 0; j < 8; j++)
                    acc[i][j] += a[i] * b[j];
        }
        __syncthreads();
    }

    float bv[8];
    #pragma unroll
    for (int j = 0; j < 8; j++) {
        int n = n0 + tn * 8 + j;
        float b = 0.0f;
        if (bias1) b += bias1[n];
        if (bias2) b += bias2[n];
        bv[j] = b;
    }
    #pragma unroll
    for (int i = 0; i < 8; i++) {
        int64_t m = m0 + tm * 8 + i;
        float o[8];
        #pragma unroll
        for (int j = 0; j < 8; j++) {
            float v = acc[i][j] + bv[j];
            if (ACT == 1) v = tanhf(v);
            o[j] = v;
        }
        *(float4*)(C + m * ldc + n0 + tn * 8)     = make_float4(o[0], o[1], o[2], o[3]);
        *(float4*)(C + m * ldc + n0 + tn * 8 + 4) = make_float4(o[4], o[5], o[6], o[7]);
    }
}

// ---------------------------------------------------------------------------
// LSTM recurrence, weight-persistent single-workgroup version.
// grid: 64 blocks (one per batch) x 512 threads = 8 waves.
// Thread t owns gate rows (2t, 2t+1). Weight source per kq u (k = 4u..4u+3):
//   u < UREG        : VGPRs (loaded once; small enough to never spill)
//   u < UREG+ULDS   : LDS   (staged once)
//   else            : streamed from L2 every step (#pragma unroll 5 keeps
//                     ~10 dwordx4/wave in flight = 80 KB/CU of MLP)
__global__ __launch_bounds__(512) void lstm_rec_kernel(
    const float* __restrict__ Ag,      // [B*T][1024] = x@Wih^T + bih + bhh
    const float4* __restrict__ Wpk,    // this layer's packed weights
    const float* __restrict__ h0,      // [B][256] this layer
    const float* __restrict__ c0,
    float* __restrict__ X, int ldx)    // h output, row b*T+t
{
    const int b = blockIdx.x;
    const int t = threadIdx.x;         // 0..511

    __shared__ __align__(16) float  hsh[HT];
    __shared__ __align__(16) float  gsh[GATES];
    __shared__ __align__(16) float4 Wl[ULDS * 2 * 512];   // 144 KB

    // --- weights into registers (40 VGPRs)
    float4 wreg[2 * UREG];
    #pragma unroll
    for (int u = 0; u < UREG; u++) {
        wreg[2 * u]     = Wpk[(u * 2 + 0) * 512 + t];
        wreg[2 * u + 1] = Wpk[(u * 2 + 1) * 512 + t];
    }
    // --- weights into LDS (once)
    #pragma unroll
    for (int v = 0; v < ULDS; v++) {
        Wl[(v * 2 + 0) * 512 + t] = Wpk[((UREG + v) * 2 + 0) * 512 + t];
        Wl[(v * 2 + 1) * 512 + t] = Wpk[((UREG + v) * 2 + 1) * 512 + t];
    }
    const float4* __restrict__ Ws = Wpk + (UREG + ULDS) * 2 * 512;

    // --- state init
    if (t < HT) hsh[t] = h0[b * HT + t];
    float c = (t < HT) ? c0[b * HT + t] : 0.0f;
    __syncthreads();

    const float4* hsh4 = (const float4*)hsh;
    const float* AgB = Ag + (int64_t)b * TT * GATES;

    for (int st = 0; st < TT; st++) {
        float2 acc = *(const float2*)(AgB + (int64_t)st * GATES + 2 * t);

        // streamed portion first: longest-latency loads issue earliest
        #pragma unroll 5
        for (int u = 0; u < USTR; u++) {
            float4 wa = Ws[(u * 2 + 0) * 512 + t];
            float4 wb = Ws[(u * 2 + 1) * 512 + t];
            float4 h4 = hsh4[UREG + ULDS + u];
            acc.x += wa.x * h4.x + wa.y * h4.y + wa.z * h4.z + wa.w * h4.w;
            acc.y += wb.x * h4.x + wb.y * h4.y + wb.z * h4.z + wb.w * h4.w;
        }
        #pragma unroll
        for (int v = 0; v < ULDS; v++) {
            float4 h4 = hsh4[UREG + v];
            float4 wa = Wl[(v * 2 + 0) * 512 + t];
            float4 wb = Wl[(v * 2 + 1) * 512 + t];
            acc.x += wa.x * h4.x + wa.y * h4.y + wa.z * h4.z + wa.w * h4.w;
            acc.y += wb.x * h4.x + wb.y * h4.y + wb.z * h4.z + wb.w * h4.w;
        }
        #pragma unroll
        for (int u = 0; u < UREG; u++) {
            float4 h4 = hsh4[u];
            float4 wa = wreg[2 * u], wb = wreg[2 * u + 1];
            acc.x += wa.x * h4.x + wa.y * h4.y + wa.z * h4.z + wa.w * h4.w;
            acc.y += wb.x * h4.x + wb.y * h4.y + wb.z * h4.z + wb.w * h4.w;
        }
        *(float2*)&gsh[2 * t] = acc;
        __syncthreads();                       // gates complete

        if (t < HT) {
            float gi = gsh[t];
            float gf = gsh[HT + t];
            float gg = gsh[2 * HT + t];
            float go = gsh[3 * HT + t];
            c = sigmoidf_(gf) * c + sigmoidf_(gi) * tanhf(gg);
            float h = sigmoidf_(go) * tanhf(c);
            X[((int64_t)b * TT + st) * ldx + t] = h;
            hsh[t] = h;                        // safe: dots done at barrier above
        }
        __syncthreads();                       // h visible for next step
    }
}

// ---------------------------------------------------------------------------
__global__ __launch_bounds__(256) void softmax512_kernel(float* __restrict__ S)
{
    int row = blockIdx.x * 4 + (threadIdx.x >> 6);
    int lane = threadIdx.x & 63;
    float* p = S + (int64_t)row * 512 + lane * 8;
    float4 v0 = *(float4*)p;
    float4 v1 = *(float4*)(p + 4);
    float m = fmaxf(fmaxf(fmaxf(v0.x, v0.y), fmaxf(v0.z, v0.w)),
                    fmaxf(fmaxf(v1.x, v1.y), fmaxf(v1.z, v1.w)));
    #pragma unroll
    for (int off = 32; off; off >>= 1) m = fmaxf(m, __shfl_xor(m, off));
    v0.x = __expf(v0.x - m); v0.y = __expf(v0.y - m);
    v0.z = __expf(v0.z - m); v0.w = __expf(v0.w - m);
    v1.x = __expf(v1.x - m); v1.y = __expf(v1.y - m);
    v1.z = __expf(v1.z - m); v1.w = __expf(v1.w - m);
    float s = v0.x + v0.y + v0.z + v0.w + v1.x + v1.y + v1.z + v1.w;
    #pragma unroll
    for (int off = 32; off; off >>= 1) s += __shfl_xor(s, off);
    float inv = 1.0f / s;
    v0.x *= inv; v0.y *= inv; v0.z *= inv; v0.w *= inv;
    v1.x *= inv; v1.y *= inv; v1.z *= inv; v1.w *= inv;
    *(float4*)p = v0;
    *(float4*)(p + 4) = v1;
}

__global__ __launch_bounds__(256) void values_kernel(
    const float* __restrict__ Q, const float* __restrict__ L, float* __restrict__ V)
{
    int row = blockIdx.x * 4 + (threadIdx.x >> 6);
    int lane = threadIdx.x & 63;
    float2 q = *(const float2*)(Q + (int64_t)row * OO + lane * 2);
    float2 l = *(const float2*)(L + (int64_t)row * OO + lane * 2);
    float s = q.x * l.x + q.y * l.y;
    #pragma unroll
    for (int off = 32; off; off >>= 1) s += __shfl_xor(s, off);
    if (lane == 0) V[row] = s;
}

// ---------------------------------------------------------------------------
extern "C" void kernel_launch(void* const* d_in, const int* in_sizes, int n_in,
                              void* d_out, int out_size, void* d_ws, size_t ws_size,
                              hipStream_t stream)
{
    const float* enc      = (const float*)d_in[0];
    const float* h0       = (const float*)d_in[1];
    const float* c0       = (const float*)d_in[2];
    const int*   actions  = (const int*)  d_in[3];
    const float* emb_t    = (const float*)d_in[4];
    const float* Wih      = (const float*)d_in[5];
    const float* Whh      = (const float*)d_in[6];
    const float* bih      = (const float*)d_in[7];
    const float* bhh      = (const float*)d_in[8];
    const float* W_attn   = (const float*)d_in[9];
    const float* b_attn   = (const float*)d_in[10];
    const float* W_concat = (const float*)d_in[11];
    const float* b_concat = (const float*)d_in[12];
    const float* W_out    = (const float*)d_in[13];
    const float* W_critic = (const float*)d_in[14];
    const float* b_critic = (const float*)d_in[15];
    (void)in_sizes; (void)n_in; (void)out_size; (void)ws_size;

    const int M = BB * TT;                 // 32768

    float* out    = (float*)d_out;
    float* dact   = out;
    float* logits = out + M;
    float* values = out + M + (int64_t)M * OO;

    // Workspace arena (floats), 256 MiB total:
    //   gates : 33,554,432   (A; later scores then qv)
    //   xbuf  :  8,388,608   (emb -> X1 -> dec)
    //   cat   : 16,777,216   ([out | ctx] row stride 512)
    //   keysR :  8,388,608   (Wpk during LSTM; keys after)
    float* ws    = (float*)d_ws;
    float* gates = ws;
    float* xbuf  = ws + 33554432;
    float* cat   = ws + 41943040;
    float* keysR = ws + 58720256;
    float* keys  = keysR;
    float4* Wpk4 = (float4*)keysR;         // 131072 float4 = 2 MB; dead before keys
    float* scores = gates;
    float* qv     = gates;
    float* dec    = xbuf;

    const int64_t LWP = 65536;             // float4s per layer in Wpk

    // 1) embedding + decoder_action
    hipLaunchKernelGGL(embed_kernel, dim3(M), dim3(256), 0, stream,
                       actions, emb_t, xbuf, dact);
    // 2) repack Whh into register/LDS/stream layout
    hipLaunchKernelGGL(repack_whh_kernel, dim3(512), dim3(256), 0, stream,
                       Whh, Wpk4);
    // 3) layer-0 input GEMM: gates = emb @ Wih0^T + bih0 + bhh0
    hipLaunchKernelGGL((gemm128_kernel<true, 0>), dim3(8, 256, 1), dim3(256), 0, stream,
                       xbuf, Wih, gates, HT, HT, HT, GATES,
                       (int64_t)0, (int64_t)0, (int64_t)0, bih, bhh);
    // 4) layer-0 recurrence -> X1 (xbuf, ldx=256)
    hipLaunchKernelGGL(lstm_rec_kernel, dim3(BB), dim3(512), 0, stream,
                       gates, Wpk4, h0, c0, xbuf, HT);
    // 5) layer-1 input GEMM
    hipLaunchKernelGGL((gemm128_kernel<true, 0>), dim3(8, 256, 1), dim3(256), 0, stream,
                       xbuf, Wih + (int64_t)GATES * HT, gates, HT, HT, HT, GATES,
                       (int64_t)0, (int64_t)0, (int64_t)0, bih + GATES, bhh + GATES);
    // 6) layer-1 recurrence -> cat[:, 0:256] (ldx=512)
    hipLaunchKernelGGL(lstm_rec_kernel, dim3(BB), dim3(512), 0, stream,
                       gates, Wpk4 + LWP, h0 + BB * HT, c0 + BB * HT, cat, 2 * HT);
    // 7) keys = enc @ W_attn^T + b_attn   (overwrites Wpk region)
    hipLaunchKernelGGL((gemm128_kernel<true, 0>), dim3(2, 256, 1), dim3(256), 0, stream,
                       enc, W_attn, keys, HT, HT, HT, HT,
                       (int64_t)0, (int64_t)0, (int64_t)0, b_attn, (const float*)nullptr);
    // 8) scores[b] = out[b] @ keys[b]^T
    hipLaunchKernelGGL((gemm128_kernel<true, 0>), dim3(4, 4, BB), dim3(256), 0, stream,
                       cat, keys, scores, HT, 2 * HT, HT, TT,
                       (int64_t)TT * 2 * HT, (int64_t)TT * HT, (int64_t)TT * TT,
                       (const float*)nullptr, (const float*)nullptr);
    // 9) softmax
    hipLaunchKernelGGL(softmax512_kernel, dim3(M / 4), dim3(256), 0, stream, scores);
    // 10) ctx[b] = P[b] @ enc[b] -> cat[:,256:]
    hipLaunchKernelGGL((gemm128_kernel<false, 0>), dim3(2, 4, BB), dim3(256), 0, stream,
                       scores, enc, cat + HT, TT, TT, HT, 2 * HT,
                       (int64_t)TT * TT, (int64_t)TT * HT, (int64_t)TT * 2 * HT,
                       (const float*)nullptr, (const float*)nullptr);
    // 11) dec = tanh(cat @ W_concat^T + b_concat)
    hipLaunchKernelGGL((gemm128_kernel<true, 1>), dim3(2, 256, 1), dim3(256), 0, stream,
                       cat, W_concat, dec, 2 * HT, 2 * HT, 2 * HT, HT,
                       (int64_t)0, (int64_t)0, (int64_t)0, b_concat, (const float*)nullptr);
    // 12) logits = dec @ W_out^T
    hipLaunchKernelGGL((gemm128_kernel<true, 0>), dim3(1, 256, 1), dim3(256), 0, stream,
                       dec, W_out, logits, HT, HT, HT, OO,
                       (int64_t)0, (int64_t)0, (int64_t)0,
                       (const float*)nullptr, (const float*)nullptr);
    // 13) qv = logits @ W_critic^T + b_critic
    hipLaunchKernelGGL((gemm128_kernel<true, 0>), dim3(1, 256, 1), dim3(256), 0, stream,
                       logits, W_critic, qv, OO, OO, OO, OO,
                       (int64_t)0, (int64_t)0, (int64_t)0, b_critic, (const float*)nullptr);
    // 14) values
    hipLaunchKernelGGL(values_kernel, dim3(M / 4), dim3(256), 0, stream,
                       qv, logits, values);
}